// Round 1
// baseline (1020.546 us; speedup 1.0000x reference)
//
#include <hip/hip_runtime.h>
#include <math.h>

#define Bsz  4
#define Nseq 2048
#define Dm   1024
#define Hh   16
#define DHd  64
#define DFFd 4096
#define EPSv 1e-5f

typedef unsigned short u16;
typedef __attribute__((ext_vector_type(8))) short bf16x8;   // 8 bf16 = 4 VGPRs
typedef __attribute__((ext_vector_type(4))) float f32x4;

__device__ inline u16 f2bf(float f) {
    union { float f; unsigned int u; } v; v.f = f;
    unsigned int r = v.u + 0x7fffu + ((v.u >> 16) & 1u);   // round-to-nearest-even
    return (u16)(r >> 16);
}

// ---------------------------------------------------------------------------
// LayerNorm: one 256-thread block per row of Dm=1024 floats. OBF: bf16 out.
// ---------------------------------------------------------------------------
template<int OBF>
__global__ __launch_bounds__(256) void ln_kernel(
    const float* __restrict__ x, const float* __restrict__ g,
    const float* __restrict__ b, void* __restrict__ outv)
{
    const int row = blockIdx.x;
    const int tid = threadIdx.x;
    const float* xr = x + (size_t)row * Dm;

    float4 v = ((const float4*)xr)[tid];
    __shared__ float red[5];

    float s = v.x + v.y + v.z + v.w;
    for (int off = 32; off; off >>= 1) s += __shfl_down(s, off, 64);
    int lane = tid & 63, wv = tid >> 6;
    if (lane == 0) red[wv] = s;
    __syncthreads();
    if (tid == 0) red[4] = (red[0] + red[1] + red[2] + red[3]) * (1.0f / Dm);
    __syncthreads();
    const float mean = red[4];

    float dx = v.x - mean, dy = v.y - mean, dz = v.z - mean, dw = v.w - mean;
    float s2 = dx*dx + dy*dy + dz*dz + dw*dw;
    for (int off = 32; off; off >>= 1) s2 += __shfl_down(s2, off, 64);
    if (lane == 0) red[wv] = s2;
    __syncthreads();
    if (tid == 0) red[4] = rsqrtf((red[0] + red[1] + red[2] + red[3]) * (1.0f / Dm) + EPSv);
    __syncthreads();
    const float inv = red[4];

    float4 gv = ((const float4*)g)[tid];
    float4 bv = ((const float4*)b)[tid];
    float ox = dx * inv * gv.x + bv.x;
    float oy = dy * inv * gv.y + bv.y;
    float oz = dz * inv * gv.z + bv.z;
    float ow = dw * inv * gv.w + bv.w;
    if (OBF) {
        ushort4 o; o.x = f2bf(ox); o.y = f2bf(oy); o.z = f2bf(oz); o.w = f2bf(ow);
        ((ushort4*)((u16*)outv + (size_t)row * Dm))[tid] = o;
    } else {
        float4 o; o.x = ox; o.y = oy; o.z = oz; o.w = ow;
        ((float4*)((float*)outv + (size_t)row * Dm))[tid] = o;
    }
}

// ---------------------------------------------------------------------------
// Weight convert+transpose: W[K][N] fp32 -> Wt[N][K] bf16. 32x32 LDS tiles.
// ---------------------------------------------------------------------------
__global__ __launch_bounds__(256) void tcvt_kernel(
    const float* __restrict__ W, u16* __restrict__ Wt, int K, int N)
{
    __shared__ float t[32][33];
    const int k0 = blockIdx.y * 32, n0 = blockIdx.x * 32;
    const int tx = threadIdx.x & 31, ty = threadIdx.x >> 5;   // ty 0..7
#pragma unroll
    for (int i = 0; i < 4; i++)
        t[ty + i*8][tx] = W[(size_t)(k0 + ty + i*8) * N + n0 + tx];
    __syncthreads();
#pragma unroll
    for (int i = 0; i < 4; i++)
        Wt[(size_t)(n0 + ty + i*8) * K + k0 + tx] = f2bf(t[tx][ty + i*8]);
}

// ---------------------------------------------------------------------------
// bf16 MFMA GEMM: C[M,Nn] = A[M,K](bf16) x Bt[Nn,K](bf16) + bias, epilogue.
// 128x128 tile, BK=32, 256 threads (4 waves, each 64x64 via 4x4 mfma tiles).
// Staging via global_load_lds(16B); LDS chunk XOR-swizzle (c ^ ((r>>1)&3)).
// EPI: 0 = bias -> f32 | 1 = bias + res(f32) -> f32 | 2 = bias + GELU -> bf16
//      3 = bias -> bf16
// ---------------------------------------------------------------------------
template<int EPI>
__global__ __launch_bounds__(256) void bgemm_kernel(
    const u16* __restrict__ A, const u16* __restrict__ Bt,
    const float* __restrict__ bias, const float* __restrict__ res,
    void* __restrict__ Cout, int M, int Nn, int K)
{
    __shared__ u16 Asl[128 * 32];   // 8 KB, row-major [r][32], chunks swizzled
    __shared__ u16 Bsl[128 * 32];   // 8 KB

    const int tid  = threadIdx.x;
    const int lane = tid & 63;
    const int w    = tid >> 6;              // wave 0..3
    const int bm   = blockIdx.y * 128;
    const int bn   = blockIdx.x * 128;
    const int wm   = (w & 1) * 64;
    const int wn   = (w >> 1) * 64;

    // ---- staging addresses: wave w stages rows [w*32, w*32+32) of A and B ----
    const int r0 = w * 32 + (lane >> 2);    // instr0 row; instr1 = r0+16
    const int r1 = r0 + 16;
    const int c  = lane & 3;
    const int cs0 = c ^ ((r0 >> 1) & 3);    // swizzled global chunk for LDS slot (r0,c)
    const int cs1 = c ^ ((r1 >> 1) & 3);
    const u16* pa0 = A  + (size_t)(bm + r0) * K + cs0 * 8;
    const u16* pa1 = A  + (size_t)(bm + r1) * K + cs1 * 8;
    const u16* pb0 = Bt + (size_t)(bn + r0) * K + cs0 * 8;
    const u16* pb1 = Bt + (size_t)(bn + r1) * K + cs1 * 8;
    u16* la0 = &Asl[(size_t)w * 1024];      // wave-uniform LDS bases
    u16* la1 = &Asl[(size_t)w * 1024 + 512];
    u16* lb0 = &Bsl[(size_t)w * 1024];
    u16* lb1 = &Bsl[(size_t)w * 1024 + 512];

    // ---- fragment LDS offsets (constant per lane) ----
    const int q  = lane >> 4;               // k-chunk 0..3
    const int fr = lane & 15;               // row within 16x16 tile
    int offA[4], offB[4];
#pragma unroll
    for (int i = 0; i < 4; i++) {
        int ra = wm + i * 16 + fr;
        offA[i] = ra * 32 + ((q ^ ((ra >> 1) & 3)) << 3);
        int rb = wn + i * 16 + fr;
        offB[i] = rb * 32 + ((q ^ ((rb >> 1) & 3)) << 3);
    }

    f32x4 acc[4][4] = {};

    const int nk = K >> 5;
    for (int kt = 0; kt < nk; kt++) {
        __syncthreads();                    // prev-iter LDS reads complete
        __builtin_amdgcn_global_load_lds(
            (const __attribute__((address_space(1))) void*)pa0,
            (__attribute__((address_space(3))) void*)la0, 16, 0, 0);
        __builtin_amdgcn_global_load_lds(
            (const __attribute__((address_space(1))) void*)pa1,
            (__attribute__((address_space(3))) void*)la1, 16, 0, 0);
        __builtin_amdgcn_global_load_lds(
            (const __attribute__((address_space(1))) void*)pb0,
            (__attribute__((address_space(3))) void*)lb0, 16, 0, 0);
        __builtin_amdgcn_global_load_lds(
            (const __attribute__((address_space(1))) void*)pb1,
            (__attribute__((address_space(3))) void*)lb1, 16, 0, 0);
        pa0 += 32; pa1 += 32; pb0 += 32; pb1 += 32;
        __syncthreads();                    // staging complete (vmcnt drained)

        bf16x8 a[4], b[4];
#pragma unroll
        for (int i = 0; i < 4; i++) a[i] = *(const bf16x8*)&Asl[offA[i]];
#pragma unroll
        for (int i = 0; i < 4; i++) b[i] = *(const bf16x8*)&Bsl[offB[i]];
#pragma unroll
        for (int mi = 0; mi < 4; mi++)
#pragma unroll
            for (int ni = 0; ni < 4; ni++)
                acc[mi][ni] = __builtin_amdgcn_mfma_f32_16x16x32_bf16(
                    a[mi], b[ni], acc[mi][ni], 0, 0, 0);
    }

    // ---- epilogue. C/D layout: col = lane&15, row = (lane>>4)*4 + reg ----
    const int erow0 = bm + wm + ((lane >> 4) << 2);
    const int ecol0 = bn + wn + (lane & 15);
#pragma unroll
    for (int ni = 0; ni < 4; ni++) {
        const int ccol = ecol0 + ni * 16;
        const float bv = bias[ccol];
#pragma unroll
        for (int mi = 0; mi < 4; mi++) {
#pragma unroll
            for (int r = 0; r < 4; r++) {
                const size_t idx = (size_t)(erow0 + mi * 16 + r) * Nn + ccol;
                float v = acc[mi][ni][r] + bv;
                if (EPI == 1) v += res[idx];
                if (EPI == 2) {
                    v = 0.5f * v * (1.0f + erff(v * 0.70710678118f));
                    ((u16*)Cout)[idx] = f2bf(v);
                } else if (EPI == 3) {
                    ((u16*)Cout)[idx] = f2bf(v);
                } else {
                    ((float*)Cout)[idx] = v;
                }
            }
        }
    }
}

// ---------------------------------------------------------------------------
// Flash attention on MFMA (bf16 QK^T and PV, fp32 online softmax).
// One 256-thread block (4 waves) per (h, q-tile of 64, b); wave w owns 16
// q-rows. K/V tiles of 64 staged in LDS as bf16 with chunk-XOR swizzle
// (slot = chunk ^ (row&7)) so fragment ds_read_b128 is conflict-free.
// qkv input is bf16 [B][N][3*Dm]. Fragment convention identical to bgemm:
// A/B-frag: lane holds row (lane&15), k = (lane>>4)*8+j (+32 per chunk);
// C/D: col = lane&15, row = (lane>>4)*4 + reg.
// ---------------------------------------------------------------------------
__global__ __launch_bounds__(256) void fattn_kernel(
    const u16* __restrict__ qkv, const float* __restrict__ sbias,
    u16* __restrict__ out)
{
    __shared__ u16 Ks[4096];   // K-tile  [k-row][d]   8 KB, swizzled
    __shared__ u16 Vt[4096];   // V-tile^T [d][m]      8 KB, swizzled
    __shared__ u16 Ps[4096];   // P       4 waves x [16 q][64 m], swizzled

    const int tid  = threadIdx.x;
    const int lane = tid & 63;
    const int w    = tid >> 6;          // wave 0..3
    const int idx  = blockIdx.x;        // ((h*32 + qt)*4 + b)
    const int b  = idx & 3;
    const int gq = idx >> 2;
    const int qt = gq & 31;
    const int h  = gq >> 5;
    const int n0 = qt * 64;

    const int grp = lane >> 4;          // 16-lane group 0..3
    const int fr  = lane & 15;

    const size_t rs = 3 * Dm;           // qkv row stride (u16 units)
    const u16* qk = qkv + (size_t)b * Nseq * rs + h * DHd;

    // ---- Q fragments: registers for the whole kernel (16 rows per wave) ----
    bf16x8 qf0, qf1;
    {
        const u16* p = qk + (size_t)(n0 + w*16 + fr) * rs + grp*8;
        qf0 = *(const bf16x8*)p;
        qf1 = *(const bf16x8*)(p + 32);
    }

    // ---- K staging: 2 global_load_lds per wave, pre-swizzled source ----
    // instr i covers LDS bytes [i*4096 + w*1024 + lane*16): row r = i*32 +
    // w*8 + (lane>>3), slot s = lane&7 -> source chunk c = s ^ (r&7).
    const int r_st = w*8 + (lane>>3);
    const int c8   = (lane&7) ^ (r_st & 7);     // (r+32)&7 == r&7
    const u16* kp0 = qk + Dm + (size_t)r_st * rs + c8*8;
    const u16* kp1 = kp0 + (size_t)32 * rs;
    u16* kl0 = &Ks[w*512];
    u16* kl1 = &Ks[2048 + w*512];

    // ---- V staging: reg-load + transposed scalar LDS stores ----
    const int vm = tid >> 2;            // m-row 0..63
    const int vd = (tid & 3) * 16;      // d-base 0/16/32/48
    const u16* vp = qk + 2*Dm + (size_t)vm * rs + vd;
    const int vslot = vm >> 3, vlow = vm & 7;

    // ---- fragment read offsets (u16 units, constant per lane) ----
    int offKV[4][2];                    // same formula serves Ks and Vt
#pragma unroll
    for (int ni = 0; ni < 4; ni++)
#pragma unroll
        for (int cc = 0; cc < 2; cc++)
            offKV[ni][cc] = (ni*16 + fr)*64 + (((grp | (cc<<2)) ^ (fr&7)) << 3);
    int offPr[2];
#pragma unroll
    for (int cc = 0; cc < 2; cc++)
        offPr[cc] = w*1024 + fr*64 + (((grp | (cc<<2)) ^ (fr&7)) << 3);

    const float* bp = sbias + ((size_t)h*Nseq + (n0 + w*16 + grp*4))*Nseq + fr;

    f32x4 acc_o[4] = {};                // [ni][reg]: col = ni*16+fr, row = grp*4+reg
    float m_r[4] = {-1e30f, -1e30f, -1e30f, -1e30f};
    float l_r[4] = {};

    for (int kt = 0; kt < Nseq/64; kt++) {
        __syncthreads();                // prev-iter K/V LDS reads complete
        __builtin_amdgcn_global_load_lds(
            (const __attribute__((address_space(1))) void*)kp0,
            (__attribute__((address_space(3))) void*)kl0, 16, 0, 0);
        __builtin_amdgcn_global_load_lds(
            (const __attribute__((address_space(1))) void*)kp1,
            (__attribute__((address_space(3))) void*)kl1, 16, 0, 0);
        kp0 += 64*rs; kp1 += 64*rs;

        bf16x8 v0 = *(const bf16x8*)vp;
        bf16x8 v1 = *(const bf16x8*)(vp + 8);
        vp += 64*rs;
#pragma unroll
        for (int j = 0; j < 8; j++) {   // Vt[d][m], slot = (m>>3) ^ (d&7)
            Vt[(vd + j)*64     + ((vslot ^ j) << 3) + vlow] = (u16)v0[j];
            Vt[(vd + 8 + j)*64 + ((vslot ^ j) << 3) + vlow] = (u16)v1[j];
        }

        float bb[4][4];                 // structural bias (fp32, exact)
#pragma unroll
        for (int r = 0; r < 4; r++)
#pragma unroll
            for (int ni = 0; ni < 4; ni++)
                bb[r][ni] = bp[(size_t)r*Nseq + kt*64 + ni*16];

        __syncthreads();                // staging visible (vmcnt+lgkm drained)

        // ---- S = Q K^T ----
        f32x4 acc_s[4] = {};
#pragma unroll
        for (int ni = 0; ni < 4; ni++) {
            bf16x8 k0 = *(const bf16x8*)&Ks[offKV[ni][0]];
            bf16x8 k1 = *(const bf16x8*)&Ks[offKV[ni][1]];
            acc_s[ni] = __builtin_amdgcn_mfma_f32_16x16x32_bf16(qf0, k0, acc_s[ni], 0, 0, 0);
            acc_s[ni] = __builtin_amdgcn_mfma_f32_16x16x32_bf16(qf1, k1, acc_s[ni], 0, 0, 0);
        }

        // ---- online softmax (per q-row = per (grp, reg)); P -> bf16 LDS ----
#pragma unroll
        for (int r = 0; r < 4; r++) {
            float s0 = acc_s[0][r]*0.125f + bb[r][0];
            float s1 = acc_s[1][r]*0.125f + bb[r][1];
            float s2 = acc_s[2][r]*0.125f + bb[r][2];
            float s3 = acc_s[3][r]*0.125f + bb[r][3];
            float tmax = fmaxf(fmaxf(s0, s1), fmaxf(s2, s3));
            tmax = fmaxf(tmax, __shfl_xor(tmax, 1, 64));
            tmax = fmaxf(tmax, __shfl_xor(tmax, 2, 64));
            tmax = fmaxf(tmax, __shfl_xor(tmax, 4, 64));
            tmax = fmaxf(tmax, __shfl_xor(tmax, 8, 64));
            const float mnew  = fmaxf(m_r[r], tmax);
            const float alpha = __expf(m_r[r] - mnew);
            float p0 = __expf(s0 - mnew), p1 = __expf(s1 - mnew);
            float p2 = __expf(s2 - mnew), p3 = __expf(s3 - mnew);
            float ss = p0 + p1 + p2 + p3;
            ss += __shfl_xor(ss, 1, 64);
            ss += __shfl_xor(ss, 2, 64);
            ss += __shfl_xor(ss, 4, 64);
            ss += __shfl_xor(ss, 8, 64);
            l_r[r] = l_r[r]*alpha + ss;
            m_r[r] = mnew;
            acc_o[0][r] *= alpha; acc_o[1][r] *= alpha;
            acc_o[2][r] *= alpha; acc_o[3][r] *= alpha;
            // P write: row q = grp*4+r, col k = ni*16+fr; slot = (k>>3)^(q&7)
            const int q  = grp*4 + r;
            const int fh = fr >> 3, qx = q & 7;
            u16* pw = &Ps[w*1024 + q*64 + (fr & 7)];
            pw[(((0|fh) ^ qx) << 3)] = f2bf(p0);
            pw[(((2|fh) ^ qx) << 3)] = f2bf(p1);
            pw[(((4|fh) ^ qx) << 3)] = f2bf(p2);
            pw[(((6|fh) ^ qx) << 3)] = f2bf(p3);
        }
        // Ps is wave-private; within-wave DS ops are in-order -> no barrier.

        // ---- O += P V ----
        bf16x8 pf0 = *(const bf16x8*)&Ps[offPr[0]];
        bf16x8 pf1 = *(const bf16x8*)&Ps[offPr[1]];
#pragma unroll
        for (int ni = 0; ni < 4; ni++) {
            bf16x8 vf0 = *(const bf16x8*)&Vt[offKV[ni][0]];
            bf16x8 vf1 = *(const bf16x8*)&Vt[offKV[ni][1]];
            acc_o[ni] = __builtin_amdgcn_mfma_f32_16x16x32_bf16(pf0, vf0, acc_o[ni], 0, 0, 0);
            acc_o[ni] = __builtin_amdgcn_mfma_f32_16x16x32_bf16(pf1, vf1, acc_o[ni], 0, 0, 0);
        }
    }

    // ---- normalize + store bf16 ----
#pragma unroll
    for (int r = 0; r < 4; r++) {
        const float invl = 1.0f / l_r[r];
        u16* orow = out + ((size_t)(b*Nseq + n0 + w*16 + grp*4 + r))*Dm + h*DHd + fr;
#pragma unroll
        for (int ni = 0; ni < 4; ni++)
            orow[ni*16] = f2bf(acc_o[ni][r] * invl);
    }
}

// ---------------------------------------------------------------------------
// Workspace (<=160MB):
//   [0,48MB)    qkv bf16 (dead after fattn) / hidden bf16 64MB (FF phase)
//   [96,112MB)  normed bf16 (ln1 out; reused for ln2 out)
//   [112,128MB) attn bf16
//   [128,152MB) transposed bf16 weights: qkv 6MB | out 2MB | ff1 8MB | ff2 8MB
// ---------------------------------------------------------------------------
extern "C" void kernel_launch(void* const* d_in, const int* in_sizes, int n_in,
                              void* d_out, int out_size, void* d_ws, size_t ws_size,
                              hipStream_t stream)
{
    const float* x     = (const float*)d_in[0];
    const float* sbias = (const float*)d_in[1];
    const float* ln1g  = (const float*)d_in[2];
    const float* ln1b  = (const float*)d_in[3];
    const float* ln2g  = (const float*)d_in[4];
    const float* ln2b  = (const float*)d_in[5];
    const float* W_qkv = (const float*)d_in[6];
    const float* b_qkv = (const float*)d_in[7];
    const float* W_out = (const float*)d_in[8];
    const float* b_out = (const float*)d_in[9];
    const float* W_ff1 = (const float*)d_in[10];
    const float* b_ff1 = (const float*)d_in[11];
    const float* W_ff2 = (const float*)d_in[12];
    const float* b_ff2 = (const float*)d_in[13];
    float* out = (float*)d_out;

    char* ws = (char*)d_ws;
    const size_t MB = 1024ull * 1024;
    u16*   qkvb   = (u16*)ws;                    // 48 MB bf16
    u16*   hidden = (u16*)ws;                    // 64 MB bf16 (FF phase)
    u16*   normed = (u16*)(ws + 96 * MB);
    u16*   attn   = (u16*)(ws + 112 * MB);
    u16*   Wqkv_t = (u16*)(ws + 128 * MB);
    u16*   Wout_t = (u16*)(ws + 134 * MB);
    u16*   Wff1_t = (u16*)(ws + 136 * MB);
    u16*   Wff2_t = (u16*)(ws + 144 * MB);

    const int M = Bsz * Nseq;   // 8192

    // 0. weight convert+transpose -> [N][K] bf16
    tcvt_kernel<<<dim3(3*Dm/32, Dm/32), 256, 0, stream>>>(W_qkv, Wqkv_t, Dm, 3*Dm);
    tcvt_kernel<<<dim3(Dm/32,   Dm/32), 256, 0, stream>>>(W_out, Wout_t, Dm, Dm);
    tcvt_kernel<<<dim3(DFFd/32, Dm/32), 256, 0, stream>>>(W_ff1, Wff1_t, Dm, DFFd);
    tcvt_kernel<<<dim3(Dm/32, DFFd/32), 256, 0, stream>>>(W_ff2, Wff2_t, DFFd, Dm);

    // 1. ln1(x) -> normed (bf16)
    ln_kernel<1><<<M, 256, 0, stream>>>(x, ln1g, ln1b, normed);
    // 2. qkv = normed @ W_qkv + b_qkv   (bf16 out for MFMA attention)
    bgemm_kernel<3><<<dim3(3*Dm/128, M/128), 256, 0, stream>>>(
        normed, Wqkv_t, b_qkv, nullptr, qkvb, M, 3*Dm, Dm);
    // 3. flash attention (MFMA) -> attn (bf16)
    fattn_kernel<<<Hh * 32 * Bsz, 256, 0, stream>>>(qkvb, sbias, attn);
    // 4. x1 = x + attn @ W_out + b_out -> d_out (fp32)
    bgemm_kernel<1><<<dim3(Dm/128, M/128), 256, 0, stream>>>(
        attn, Wout_t, b_out, x, out, M, Dm, Dm);
    // 5. ln2(x1) -> normed (bf16)
    ln_kernel<1><<<M, 256, 0, stream>>>(out, ln2g, ln2b, normed);
    // 6. hidden = gelu(normed @ W_ff1 + b_ff1) (bf16)
    bgemm_kernel<2><<<dim3(DFFd/128, M/128), 256, 0, stream>>>(
        normed, Wff1_t, b_ff1, nullptr, hidden, M, DFFd, Dm);
    // 7. out = x1 + hidden @ W_ff2 + b_ff2  (in-place on d_out)
    bgemm_kernel<1><<<dim3(Dm/128, M/128), 256, 0, stream>>>(
        hidden, Wff2_t, b_ff2, out, out, M, Dm, DFFd);
}

// Round 2
// 974.414 us; speedup vs baseline: 1.0473x; 1.0473x over previous
//
#include <hip/hip_runtime.h>
#include <math.h>

#define Bsz  4
#define Nseq 2048
#define Dm   1024
#define Hh   16
#define DHd  64
#define DFFd 4096
#define EPSv 1e-5f
#define MFIX 8.0f

typedef unsigned short u16;
typedef __attribute__((ext_vector_type(8))) short bf16x8;   // 8 bf16 = 4 VGPRs
typedef __attribute__((ext_vector_type(4))) float f32x4;

#define GLL(src, dst) __builtin_amdgcn_global_load_lds( \
    (const __attribute__((address_space(1))) void*)(src), \
    (__attribute__((address_space(3))) void*)(dst), 16, 0, 0)

__device__ inline u16 f2bf(float f) {
    union { float f; unsigned int u; } v; v.f = f;
    unsigned int r = v.u + 0x7fffu + ((v.u >> 16) & 1u);   // round-to-nearest-even
    return (u16)(r >> 16);
}

// ---------------------------------------------------------------------------
// LayerNorm: one 256-thread block per row of Dm=1024 floats. OBF: bf16 out.
// ---------------------------------------------------------------------------
template<int OBF>
__global__ __launch_bounds__(256) void ln_kernel(
    const float* __restrict__ x, const float* __restrict__ g,
    const float* __restrict__ b, void* __restrict__ outv)
{
    const int row = blockIdx.x;
    const int tid = threadIdx.x;
    const float* xr = x + (size_t)row * Dm;

    float4 v = ((const float4*)xr)[tid];
    __shared__ float red[5];

    float s = v.x + v.y + v.z + v.w;
    for (int off = 32; off; off >>= 1) s += __shfl_down(s, off, 64);
    int lane = tid & 63, wv = tid >> 6;
    if (lane == 0) red[wv] = s;
    __syncthreads();
    if (tid == 0) red[4] = (red[0] + red[1] + red[2] + red[3]) * (1.0f / Dm);
    __syncthreads();
    const float mean = red[4];

    float dx = v.x - mean, dy = v.y - mean, dz = v.z - mean, dw = v.w - mean;
    float s2 = dx*dx + dy*dy + dz*dz + dw*dw;
    for (int off = 32; off; off >>= 1) s2 += __shfl_down(s2, off, 64);
    if (lane == 0) red[wv] = s2;
    __syncthreads();
    if (tid == 0) red[4] = rsqrtf((red[0] + red[1] + red[2] + red[3]) * (1.0f / Dm) + EPSv);
    __syncthreads();
    const float inv = red[4];

    float4 gv = ((const float4*)g)[tid];
    float4 bv = ((const float4*)b)[tid];
    float ox = dx * inv * gv.x + bv.x;
    float oy = dy * inv * gv.y + bv.y;
    float oz = dz * inv * gv.z + bv.z;
    float ow = dw * inv * gv.w + bv.w;
    if (OBF) {
        ushort4 o; o.x = f2bf(ox); o.y = f2bf(oy); o.z = f2bf(oz); o.w = f2bf(ow);
        ((ushort4*)((u16*)outv + (size_t)row * Dm))[tid] = o;
    } else {
        float4 o; o.x = ox; o.y = oy; o.z = oz; o.w = ow;
        ((float4*)((float*)outv + (size_t)row * Dm))[tid] = o;
    }
}

// ---------------------------------------------------------------------------
// Weight convert+transpose: W[K][N] fp32 -> Wt[N][K] bf16. 32x32 LDS tiles.
// ---------------------------------------------------------------------------
__global__ __launch_bounds__(256) void tcvt_kernel(
    const float* __restrict__ W, u16* __restrict__ Wt, int K, int N)
{
    __shared__ float t[32][33];
    const int k0 = blockIdx.y * 32, n0 = blockIdx.x * 32;
    const int tx = threadIdx.x & 31, ty = threadIdx.x >> 5;   // ty 0..7
#pragma unroll
    for (int i = 0; i < 4; i++)
        t[ty + i*8][tx] = W[(size_t)(k0 + ty + i*8) * N + n0 + tx];
    __syncthreads();
#pragma unroll
    for (int i = 0; i < 4; i++)
        Wt[(size_t)(n0 + ty + i*8) * K + k0 + tx] = f2bf(t[tx][ty + i*8]);
}

// ---------------------------------------------------------------------------
// bf16 MFMA GEMM: C[M,Nn] = A[M,K](bf16) x Bt[Nn,K](bf16) + bias, epilogue.
// 128x128 tile, BK=32, 256 threads (4 waves, each 64x64 via 4x4 mfma tiles).
// Double-buffered LDS; prefetch issued BEFORE compute; ONE barrier per K-step
// (loads fly across the whole compute phase, drained at the barrier).
// EPI: 0 = bias -> f32 | 1 = bias + res(f32) -> f32 | 2 = bias + GELU -> bf16
//      3 = bias -> bf16 (cols < 2Dm) + V^T side-write (cols >= 2Dm -> vt)
// ---------------------------------------------------------------------------
template<int EPI>
__global__ __launch_bounds__(256) void bgemm_kernel(
    const u16* __restrict__ A, const u16* __restrict__ Bt,
    const float* __restrict__ bias, const float* __restrict__ res,
    void* __restrict__ Cout, u16* __restrict__ vt, int M, int Nn, int K)
{
    __shared__ u16 Asl[2][4096];   // 2 x 8 KB, row-major [r][32], chunks swizzled
    __shared__ u16 Bsl[2][4096];

    const int tid  = threadIdx.x;
    const int lane = tid & 63;
    const int w    = tid >> 6;              // wave 0..3
    const int bm   = blockIdx.y * 128;
    const int bn   = blockIdx.x * 128;
    const int wm   = (w & 1) * 64;
    const int wn   = (w >> 1) * 64;

    // ---- staging addresses: wave w stages rows [w*32, w*32+32) of A and B ----
    const int r0 = w * 32 + (lane >> 2);    // instr0 row; instr1 = r0+16
    const int r1 = r0 + 16;
    const int c  = lane & 3;
    const int cs0 = c ^ ((r0 >> 1) & 3);    // swizzled global chunk for LDS slot (r0,c)
    const int cs1 = c ^ ((r1 >> 1) & 3);
    const u16* pa0 = A  + (size_t)(bm + r0) * K + cs0 * 8;
    const u16* pa1 = A  + (size_t)(bm + r1) * K + cs1 * 8;
    const u16* pb0 = Bt + (size_t)(bn + r0) * K + cs0 * 8;
    const u16* pb1 = Bt + (size_t)(bn + r1) * K + cs1 * 8;

    // ---- fragment LDS offsets (constant per lane) ----
    const int q  = lane >> 4;               // k-chunk 0..3
    const int fr = lane & 15;               // row within 16x16 tile
    int offA[4], offB[4];
#pragma unroll
    for (int i = 0; i < 4; i++) {
        int ra = wm + i * 16 + fr;
        offA[i] = ra * 32 + ((q ^ ((ra >> 1) & 3)) << 3);
        int rb = wn + i * 16 + fr;
        offB[i] = rb * 32 + ((q ^ ((rb >> 1) & 3)) << 3);
    }

    f32x4 acc[4][4] = {};

    // ---- prologue: stage K-step 0 into buf 0 ----
    GLL(pa0, &Asl[0][w*1024]);      GLL(pa1, &Asl[0][w*1024 + 512]);
    GLL(pb0, &Bsl[0][w*1024]);      GLL(pb1, &Bsl[0][w*1024 + 512]);
    pa0 += 32; pa1 += 32; pb0 += 32; pb1 += 32;
    __syncthreads();

    const int nk = K >> 5;
    for (int kt = 0; kt < nk; kt++) {
        const int cur = kt & 1;
        if (kt + 1 < nk) {                  // prefetch next step into other buf
            const int nx = cur ^ 1;
            GLL(pa0, &Asl[nx][w*1024]);     GLL(pa1, &Asl[nx][w*1024 + 512]);
            GLL(pb0, &Bsl[nx][w*1024]);     GLL(pb1, &Bsl[nx][w*1024 + 512]);
            pa0 += 32; pa1 += 32; pb0 += 32; pb1 += 32;
        }

        bf16x8 a[4], b[4];
#pragma unroll
        for (int i = 0; i < 4; i++) a[i] = *(const bf16x8*)&Asl[cur][offA[i]];
#pragma unroll
        for (int i = 0; i < 4; i++) b[i] = *(const bf16x8*)&Bsl[cur][offB[i]];
#pragma unroll
        for (int mi = 0; mi < 4; mi++)
#pragma unroll
            for (int ni = 0; ni < 4; ni++)
                acc[mi][ni] = __builtin_amdgcn_mfma_f32_16x16x32_bf16(
                    a[mi], b[ni], acc[mi][ni], 0, 0, 0);

        __syncthreads();                    // next buf staged; cur free for kt+2
    }

    // ---- epilogue. C/D layout: col = lane&15, row = (lane>>4)*4 + reg ----
    const int erow0 = bm + wm + ((lane >> 4) << 2);
    const int ecol0 = bn + wn + (lane & 15);
    const bool isV = (EPI == 3) && (bn >= 2 * Dm);   // uniform per block
#pragma unroll
    for (int ni = 0; ni < 4; ni++) {
        const int ccol = ecol0 + ni * 16;
        const float bv = bias[ccol];
#pragma unroll
        for (int mi = 0; mi < 4; mi++) {
            if (isV) {
                // V columns -> transposed bf16 buffer vt[b][h*64+d][n] (ushort4)
                ushort4 o;
                o.x = f2bf(acc[mi][ni][0] + bv);
                o.y = f2bf(acc[mi][ni][1] + bv);
                o.z = f2bf(acc[mi][ni][2] + bv);
                o.w = f2bf(acc[mi][ni][3] + bv);
                const int nrow = erow0 + mi * 16;        // multiple of 4
                const int bb_  = nrow >> 11, nn = nrow & 2047;
                const int hd   = ccol - 2 * Dm;
                *(ushort4*)&vt[((size_t)(bb_ * (Hh * DHd) + hd)) * Nseq + nn] = o;
            } else {
#pragma unroll
                for (int r = 0; r < 4; r++) {
                    const size_t idx = (size_t)(erow0 + mi * 16 + r) * Nn + ccol;
                    float v = acc[mi][ni][r] + bv;
                    if (EPI == 1) v += res[idx];
                    if (EPI == 2) {
                        v = 0.5f * v * (1.0f + erff(v * 0.70710678118f));
                        ((u16*)Cout)[idx] = f2bf(v);
                    } else if (EPI == 3) {
                        ((u16*)Cout)[idx] = f2bf(v);
                    } else {
                        ((float*)Cout)[idx] = v;
                    }
                }
            }
        }
    }
}

// ---------------------------------------------------------------------------
// Flash attention, MFMA, swapped QK^T + fixed-max softmax.
// One 256-thread block (4 waves) per (h, q-tile of 128, b); wave owns 32 rows.
// S^T = mfma(K, Q): lane fr owns q-row (rb*16+fr); m = ni*16+grp*4+r in-lane.
// softmax: p = exp(s - MFIX), NO max-tracking (s bounded << MFIX; ratios are
// exact for any fixed shift). l accumulated per-lane, grp-reduced at end.
// V comes pre-transposed from the QKV GEMM (vt[b][h*64+d][n]) -> staged with
// global_load_lds like K. K/V double-buffered; ONE barrier per kv-tile.
// P: 4 x ds_write_b64 per rb (packed ushort4), read back as A-frag (b128).
// ---------------------------------------------------------------------------
__global__ __launch_bounds__(256, 3) void fattn_kernel(
    const u16* __restrict__ qkv, const u16* __restrict__ vtg,
    const float* __restrict__ sbias, u16* __restrict__ out)
{
    __shared__ u16 Ks[2][4096];   // K-tile [m 64][d 64] bf16, chunk-swizzled
    __shared__ u16 Vs[2][4096];   // V^T-tile [d 64][m 64] bf16, chunk-swizzled
    __shared__ u16 Ps[8192];      // P: 4 waves x [32 q][64 m], chunk-swizzled

    const int tid  = threadIdx.x;
    const int lane = tid & 63;
    const int w    = tid >> 6;          // wave 0..3
    const int idx  = blockIdx.x;        // ((h*16 + qt)*4 + b)
    const int b  = idx & 3;
    const int g  = idx >> 2;
    const int qt = g & 15;
    const int h  = g >> 4;
    const int n0 = qt * 128;

    const int grp = lane >> 4;          // 16-lane group 0..3
    const int fr  = lane & 15;

    const size_t rs = 3 * Dm;           // qkv row stride (u16 units)
    const u16* qk = qkv + (size_t)b * Nseq * rs + h * DHd;

    // ---- Q fragments in registers (32 rows per wave: rb = 0,1) ----
    bf16x8 qf[2][2];
#pragma unroll
    for (int rb = 0; rb < 2; rb++)
#pragma unroll
        for (int cc = 0; cc < 2; cc++)
            qf[rb][cc] = *(const bf16x8*)(
                qk + (size_t)(n0 + w*32 + rb*16 + fr) * rs + cc*32 + grp*8);

    // ---- staging source addresses (pre-swizzled chunk) ----
    const int r_st = w*8 + (lane >> 3);         // row within tile (instr1: +32)
    const int c8   = (lane & 7) ^ (r_st & 7);   // source chunk for LDS slot
    const u16* kp = qk + Dm + (size_t)r_st * rs + c8*8;
    const u16* vp = vtg + ((size_t)(b*Hh + h)*DHd + r_st) * Nseq + c8*8;

    // ---- fragment read offsets (u16 units, constant per lane) ----
    int offKV[4][2];
#pragma unroll
    for (int ni = 0; ni < 4; ni++)
#pragma unroll
        for (int cc = 0; cc < 2; cc++)
            offKV[ni][cc] = (ni*16 + fr)*64 + (((grp | (cc<<2)) ^ (fr&7)) << 3);
    const int psbase = w*2048 + fr*64;
    int offP[2][2];
#pragma unroll
    for (int rb = 0; rb < 2; rb++)
#pragma unroll
        for (int cc = 0; cc < 2; cc++)
            offP[rb][cc] = psbase + rb*1024 + (((grp | (cc<<2)) ^ (fr&7)) << 3);

    const float* bpr = sbias + ((size_t)h*Nseq + (n0 + w*32 + fr))*Nseq + grp*4;

    f32x4 acc_o[2][4] = {};             // [rb][ni]: O[q=rb*16+grp*4+r][d=ni*16+fr]
    float l_r[2] = {0.f, 0.f};

    // ---- prologue: stage kv-tile 0 ----
    GLL(kp,                     &Ks[0][w*512]);
    GLL(kp + 32*rs,             &Ks[0][2048 + w*512]);
    GLL(vp,                     &Vs[0][w*512]);
    GLL(vp + (size_t)32*Nseq,   &Vs[0][2048 + w*512]);
    kp += 64*rs; vp += 64;
    __syncthreads();

    for (int kt = 0; kt < Nseq/64; kt++) {
        const int cur = kt & 1;

        // bias prefetch (coalesced float4: lanes fr->rows, grp->16B chunks)
        float4 bb[2][4];
        const float* bp = bpr + kt*64;
#pragma unroll
        for (int rb = 0; rb < 2; rb++)
#pragma unroll
            for (int ni = 0; ni < 4; ni++)
                bb[rb][ni] = *(const float4*)(bp + (size_t)rb*(16*Nseq) + ni*16);

        if (kt + 1 < Nseq/64) {         // prefetch next kv-tile
            const int nx = cur ^ 1;
            GLL(kp,                     &Ks[nx][w*512]);
            GLL(kp + 32*rs,             &Ks[nx][2048 + w*512]);
            GLL(vp,                     &Vs[nx][w*512]);
            GLL(vp + (size_t)32*Nseq,   &Vs[nx][2048 + w*512]);
            kp += 64*rs; vp += 64;
        }

        // ---- S^T = K Q^T : A=K rows m, B=Q rows q ----
        f32x4 acc_s[2][4] = {};
#pragma unroll
        for (int ni = 0; ni < 4; ni++) {
            bf16x8 k0 = *(const bf16x8*)&Ks[cur][offKV[ni][0]];
            bf16x8 k1 = *(const bf16x8*)&Ks[cur][offKV[ni][1]];
            acc_s[0][ni] = __builtin_amdgcn_mfma_f32_16x16x32_bf16(k0, qf[0][0], acc_s[0][ni], 0, 0, 0);
            acc_s[0][ni] = __builtin_amdgcn_mfma_f32_16x16x32_bf16(k1, qf[0][1], acc_s[0][ni], 0, 0, 0);
            acc_s[1][ni] = __builtin_amdgcn_mfma_f32_16x16x32_bf16(k0, qf[1][0], acc_s[1][ni], 0, 0, 0);
            acc_s[1][ni] = __builtin_amdgcn_mfma_f32_16x16x32_bf16(k1, qf[1][1], acc_s[1][ni], 0, 0, 0);
        }

        // ---- fixed-max softmax (no shuffles) + packed P write ----
#pragma unroll
        for (int rb = 0; rb < 2; rb++) {
            float lacc = 0.f;
#pragma unroll
            for (int ni = 0; ni < 4; ni++) {
                float p0 = __expf(fmaf(acc_s[rb][ni][0], 0.125f, bb[rb][ni].x) - MFIX);
                float p1 = __expf(fmaf(acc_s[rb][ni][1], 0.125f, bb[rb][ni].y) - MFIX);
                float p2 = __expf(fmaf(acc_s[rb][ni][2], 0.125f, bb[rb][ni].z) - MFIX);
                float p3 = __expf(fmaf(acc_s[rb][ni][3], 0.125f, bb[rb][ni].w) - MFIX);
                ushort4 o;
                o.x = f2bf(p0); o.y = f2bf(p1); o.z = f2bf(p2); o.w = f2bf(p3);
                // P[q=rb*16+fr][m0=ni*16+grp*4]; chunk=ni*2+(grp>>1), slot=c^(q&7)
                const int slot = (ni*2 + (grp>>1)) ^ (fr & 7);
                *(ushort4*)&Ps[psbase + rb*1024 + slot*8 + (grp&1)*4] = o;
                lacc += (p0 + p1) + (p2 + p3);
            }
            l_r[rb] += lacc;
        }

        // ---- O += P V : A=P rows q, B=V^T rows d ----
        bf16x8 pf[2][2];
#pragma unroll
        for (int rb = 0; rb < 2; rb++)
#pragma unroll
            for (int cc = 0; cc < 2; cc++)
                pf[rb][cc] = *(const bf16x8*)&Ps[offP[rb][cc]];
#pragma unroll
        for (int ni = 0; ni < 4; ni++) {
            bf16x8 v0 = *(const bf16x8*)&Vs[cur][offKV[ni][0]];
            bf16x8 v1 = *(const bf16x8*)&Vs[cur][offKV[ni][1]];
            acc_o[0][ni] = __builtin_amdgcn_mfma_f32_16x16x32_bf16(pf[0][0], v0, acc_o[0][ni], 0, 0, 0);
            acc_o[0][ni] = __builtin_amdgcn_mfma_f32_16x16x32_bf16(pf[0][1], v1, acc_o[0][ni], 0, 0, 0);
            acc_o[1][ni] = __builtin_amdgcn_mfma_f32_16x16x32_bf16(pf[1][0], v0, acc_o[1][ni], 0, 0, 0);
            acc_o[1][ni] = __builtin_amdgcn_mfma_f32_16x16x32_bf16(pf[1][1], v1, acc_o[1][ni], 0, 0, 0);
        }

        __syncthreads();                // next tile staged; cur free
    }

    // ---- finalize: grp-reduce l, broadcast to output lanes, store bf16 ----
#pragma unroll
    for (int rb = 0; rb < 2; rb++) {
        float l = l_r[rb];
        l += __shfl_xor(l, 16, 64);
        l += __shfl_xor(l, 32, 64);
        l_r[rb] = l;                    // lane holds total l for q-row fr
    }
#pragma unroll
    for (int rb = 0; rb < 2; rb++)
#pragma unroll
        for (int r = 0; r < 4; r++) {
            const int srcl = (lane & 48) | (((lane >> 4) & 3) << 2) | r;
            const float invl = 1.0f / __shfl(l_r[rb], srcl, 64);
            u16* orow = out + ((size_t)(b*Nseq + n0 + w*32 + rb*16 + grp*4 + r))*Dm
                        + h*DHd + fr;
#pragma unroll
            for (int ni = 0; ni < 4; ni++)
                orow[ni*16] = f2bf(acc_o[rb][ni][r] * invl);
        }
}

// ---------------------------------------------------------------------------
// Workspace (<=160MB):
//   [0,48MB)    qkv bf16 (Q,K parts; dead after fattn)
//   [48,64MB)   vT bf16 [b][h*64+d][n] (dead after fattn)
//   [0,64MB)    hidden bf16 (FF phase, overlaps the two above)
//   [96,112MB)  normed bf16 (ln1 out; reused for ln2 out)
//   [112,128MB) attn bf16
//   [128,152MB) transposed bf16 weights: qkv 6MB | out 2MB | ff1 8MB | ff2 8MB
// ---------------------------------------------------------------------------
extern "C" void kernel_launch(void* const* d_in, const int* in_sizes, int n_in,
                              void* d_out, int out_size, void* d_ws, size_t ws_size,
                              hipStream_t stream)
{
    const float* x     = (const float*)d_in[0];
    const float* sbias = (const float*)d_in[1];
    const float* ln1g  = (const float*)d_in[2];
    const float* ln1b  = (const float*)d_in[3];
    const float* ln2g  = (const float*)d_in[4];
    const float* ln2b  = (const float*)d_in[5];
    const float* W_qkv = (const float*)d_in[6];
    const float* b_qkv = (const float*)d_in[7];
    const float* W_out = (const float*)d_in[8];
    const float* b_out = (const float*)d_in[9];
    const float* W_ff1 = (const float*)d_in[10];
    const float* b_ff1 = (const float*)d_in[11];
    const float* W_ff2 = (const float*)d_in[12];
    const float* b_ff2 = (const float*)d_in[13];
    float* out = (float*)d_out;

    char* ws = (char*)d_ws;
    const size_t MB = 1024ull * 1024;
    u16*   qkvb   = (u16*)ws;                    // 48 MB bf16 (Q,K live)
    u16*   vT     = (u16*)(ws + 48 * MB);        // 16 MB bf16 V^T
    u16*   hidden = (u16*)ws;                    // 64 MB bf16 (FF phase)
    u16*   normed = (u16*)(ws + 96 * MB);
    u16*   attn   = (u16*)(ws + 112 * MB);
    u16*   Wqkv_t = (u16*)(ws + 128 * MB);
    u16*   Wout_t = (u16*)(ws + 134 * MB);
    u16*   Wff1_t = (u16*)(ws + 136 * MB);
    u16*   Wff2_t = (u16*)(ws + 144 * MB);

    const int M = Bsz * Nseq;   // 8192

    // 0. weight convert+transpose -> [N][K] bf16
    tcvt_kernel<<<dim3(3*Dm/32, Dm/32), 256, 0, stream>>>(W_qkv, Wqkv_t, Dm, 3*Dm);
    tcvt_kernel<<<dim3(Dm/32,   Dm/32), 256, 0, stream>>>(W_out, Wout_t, Dm, Dm);
    tcvt_kernel<<<dim3(DFFd/32, Dm/32), 256, 0, stream>>>(W_ff1, Wff1_t, Dm, DFFd);
    tcvt_kernel<<<dim3(Dm/32, DFFd/32), 256, 0, stream>>>(W_ff2, Wff2_t, DFFd, Dm);

    // 1. ln1(x) -> normed (bf16)
    ln_kernel<1><<<M, 256, 0, stream>>>(x, ln1g, ln1b, normed);
    // 2. qkv = normed @ W_qkv + b_qkv   (Q,K -> qkvb bf16; V -> vT transposed)
    bgemm_kernel<3><<<dim3(3*Dm/128, M/128), 256, 0, stream>>>(
        normed, Wqkv_t, b_qkv, nullptr, qkvb, vT, M, 3*Dm, Dm);
    // 3. flash attention (MFMA, swapped QK^T, fixed-max softmax) -> attn (bf16)
    fattn_kernel<<<Hh * (Nseq/128) * Bsz, 256, 0, stream>>>(qkvb, vT, sbias, attn);
    // 4. x1 = x + attn @ W_out + b_out -> d_out (fp32)
    bgemm_kernel<1><<<dim3(Dm/128, M/128), 256, 0, stream>>>(
        attn, Wout_t, b_out, x, out, nullptr, M, Dm, Dm);
    // 5. ln2(x1) -> normed (bf16)
    ln_kernel<1><<<M, 256, 0, stream>>>(out, ln2g, ln2b, normed);
    // 6. hidden = gelu(normed @ W_ff1 + b_ff1) (bf16)
    bgemm_kernel<2><<<dim3(DFFd/128, M/128), 256, 0, stream>>>(
        normed, Wff1_t, b_ff1, nullptr, hidden, nullptr, M, DFFd, Dm);
    // 7. out = x1 + hidden @ W_ff2 + b_ff2  (in-place on d_out)
    bgemm_kernel<1><<<dim3(Dm/128, M/128), 256, 0, stream>>>(
        hidden, Wff2_t, b_ff2, out, out, nullptr, M, Dm, DFFd);
}

// Round 3
// 917.878 us; speedup vs baseline: 1.1119x; 1.0616x over previous
//
#include <hip/hip_runtime.h>
#include <math.h>

#define Bsz  4
#define Nseq 2048
#define Dm   1024
#define Hh   16
#define DHd  64
#define DFFd 4096
#define EPSv 1e-5f
#define MFIX 8.0f

typedef unsigned short u16;
typedef __attribute__((ext_vector_type(8))) short bf16x8;   // 8 bf16 = 4 VGPRs
typedef __attribute__((ext_vector_type(4))) float f32x4;

#define GLL(src, dst) __builtin_amdgcn_global_load_lds( \
    (const __attribute__((address_space(1))) void*)(src), \
    (__attribute__((address_space(3))) void*)(dst), 16, 0, 0)

__device__ inline u16 f2bf(float f) {
    union { float f; unsigned int u; } v; v.f = f;
    unsigned int r = v.u + 0x7fffu + ((v.u >> 16) & 1u);   // round-to-nearest-even
    return (u16)(r >> 16);
}

// ---------------------------------------------------------------------------
// LayerNorm: one 256-thread block per row of Dm=1024 floats. OBF: bf16 out.
// ---------------------------------------------------------------------------
template<int OBF>
__global__ __launch_bounds__(256) void ln_kernel(
    const float* __restrict__ x, const float* __restrict__ g,
    const float* __restrict__ b, void* __restrict__ outv)
{
    const int row = blockIdx.x;
    const int tid = threadIdx.x;
    const float* xr = x + (size_t)row * Dm;

    float4 v = ((const float4*)xr)[tid];
    __shared__ float red[5];

    float s = v.x + v.y + v.z + v.w;
    for (int off = 32; off; off >>= 1) s += __shfl_down(s, off, 64);
    int lane = tid & 63, wv = tid >> 6;
    if (lane == 0) red[wv] = s;
    __syncthreads();
    if (tid == 0) red[4] = (red[0] + red[1] + red[2] + red[3]) * (1.0f / Dm);
    __syncthreads();
    const float mean = red[4];

    float dx = v.x - mean, dy = v.y - mean, dz = v.z - mean, dw = v.w - mean;
    float s2 = dx*dx + dy*dy + dz*dz + dw*dw;
    for (int off = 32; off; off >>= 1) s2 += __shfl_down(s2, off, 64);
    if (lane == 0) red[wv] = s2;
    __syncthreads();
    if (tid == 0) red[4] = rsqrtf((red[0] + red[1] + red[2] + red[3]) * (1.0f / Dm) + EPSv);
    __syncthreads();
    const float inv = red[4];

    float4 gv = ((const float4*)g)[tid];
    float4 bv = ((const float4*)b)[tid];
    float ox = dx * inv * gv.x + bv.x;
    float oy = dy * inv * gv.y + bv.y;
    float oz = dz * inv * gv.z + bv.z;
    float ow = dw * inv * gv.w + bv.w;
    if (OBF) {
        ushort4 o; o.x = f2bf(ox); o.y = f2bf(oy); o.z = f2bf(oz); o.w = f2bf(ow);
        ((ushort4*)((u16*)outv + (size_t)row * Dm))[tid] = o;
    } else {
        float4 o; o.x = ox; o.y = oy; o.z = oz; o.w = ow;
        ((float4*)((float*)outv + (size_t)row * Dm))[tid] = o;
    }
}

// ---------------------------------------------------------------------------
// Weight convert+transpose: W[K][N] fp32 -> Wt[N][K] bf16. 32x32 LDS tiles.
// ---------------------------------------------------------------------------
__global__ __launch_bounds__(256) void tcvt_kernel(
    const float* __restrict__ W, u16* __restrict__ Wt, int K, int N)
{
    __shared__ float t[32][33];
    const int k0 = blockIdx.y * 32, n0 = blockIdx.x * 32;
    const int tx = threadIdx.x & 31, ty = threadIdx.x >> 5;   // ty 0..7
#pragma unroll
    for (int i = 0; i < 4; i++)
        t[ty + i*8][tx] = W[(size_t)(k0 + ty + i*8) * N + n0 + tx];
    __syncthreads();
#pragma unroll
    for (int i = 0; i < 4; i++)
        Wt[(size_t)(n0 + ty + i*8) * K + k0 + tx] = f2bf(t[tx][ty + i*8]);
}

// ---------------------------------------------------------------------------
// bf16 MFMA GEMM, 256-wide tiles, 512 threads (8 waves), BK=64, 2-phase
// double-buffered pipeline (stage-next -> compute-cur -> barrier).
// BM=256 always; BN in {256,128}. BN=256: waves 2Mx4N (wave C=128x64, MI=8).
// BN=128: waves 4Mx2N (wave C=64x64, MI=4). Chunk-XOR LDS swizzle
// (slot = chunk ^ (row&7)); staging via global_load_lds(16B), pre-swizzled src.
// EPI: 0 = bias -> f32 | 1 = bias + res(f32) -> f32 | 2 = bias + GELU -> bf16
//      3 = bias -> bf16 (cols < 2Dm) + V^T side-write (cols >= 2Dm -> vt)
// ---------------------------------------------------------------------------
template<int EPI, int BM, int BN>
__global__ __launch_bounds__(512, 2) void bgemm_kernel(
    const u16* __restrict__ A, const u16* __restrict__ Bt,
    const float* __restrict__ bias, const float* __restrict__ res,
    void* __restrict__ Cout, u16* __restrict__ vt, int M, int Nn, int K)
{
    constexpr int WGN = (BN == 256) ? 4 : 2;   // wave grid N
    constexpr int WGM = 8 / WGN;               // wave grid M
    constexpr int MI  = BM / WGM / 16;         // M fragments per wave (8 or 4)
    constexpr int NI  = BN / WGN / 16;         // N fragments per wave (4)
    constexpr int AG  = BM / 64;               // A GLLs per wave per K-tile (4)
    constexpr int BG  = BN / 64;               // B GLLs per wave (4 or 2)

    __shared__ u16 Asl[2][BM * 64];            // [row][8 chunks of 8 bf16]
    __shared__ u16 Bsl[2][BN * 64];

    const int tid  = threadIdx.x;
    const int lane = tid & 63;
    const int w    = tid >> 6;                 // wave 0..7
    const int bm   = blockIdx.y * BM;
    const int bn   = blockIdx.x * BN;
    const int wm   = (w % WGM) * (MI * 16);
    const int wn   = (w / WGM) * (NI * 16);

    // ---- staging: wave w stages A rows [w*32,+32), B rows [w*BN/8,+BN/8) ----
    const int lr = lane >> 3;                  // row within 8-row group
    const int c8 = (lane & 7) ^ lr;            // pre-swizzled source chunk
    const u16* pa = A  + (size_t)(bm + w * 32 + lr) * K + c8 * 8;
    const u16* pb = Bt + (size_t)(bn + w * (BN / 8) + lr) * K + c8 * 8;

#define BSTAGE(bufi) do {                                                   \
    _Pragma("unroll")                                                       \
    for (int i = 0; i < AG; i++)                                            \
        GLL(pa + (size_t)i * 8 * K, &Asl[bufi][(w * 32 + i * 8) * 64]);     \
    _Pragma("unroll")                                                       \
    for (int i = 0; i < BG; i++)                                            \
        GLL(pb + (size_t)i * 8 * K, &Bsl[bufi][(w * (BN / 8) + i * 8) * 64]); \
    pa += 64; pb += 64;                                                     \
} while (0)

    // ---- fragment LDS offsets (u16 units, constant per lane) ----
    const int grp = lane >> 4;                 // k-subchunk 0..3
    const int fr  = lane & 15;                 // row within 16x16 tile
    int offA[MI][2], offB[NI][2];
#pragma unroll
    for (int mi = 0; mi < MI; mi++)
#pragma unroll
        for (int ks = 0; ks < 2; ks++) {
            const int row = wm + mi * 16 + fr;
            offA[mi][ks] = row * 64 + (((ks * 4 + grp) ^ (row & 7)) << 3);
        }
#pragma unroll
    for (int ni = 0; ni < NI; ni++)
#pragma unroll
        for (int ks = 0; ks < 2; ks++) {
            const int row = wn + ni * 16 + fr;
            offB[ni][ks] = row * 64 + (((ks * 4 + grp) ^ (row & 7)) << 3);
        }

    f32x4 acc[MI][NI] = {};

    BSTAGE(0);                                 // prologue: K-tile 0 -> buf 0
    __syncthreads();

    const int nk = K >> 6;
    for (int kt = 0; kt < nk; kt++) {
        const int cur = kt & 1;
        if (kt + 1 < nk) {                     // issue next-tile loads FIRST
            const int nx = cur ^ 1;
            BSTAGE(nx);
        }
#pragma unroll
        for (int ks = 0; ks < 2; ks++) {
            bf16x8 a[MI], b[NI];
#pragma unroll
            for (int mi = 0; mi < MI; mi++) a[mi] = *(const bf16x8*)&Asl[cur][offA[mi][ks]];
#pragma unroll
            for (int ni = 0; ni < NI; ni++) b[ni] = *(const bf16x8*)&Bsl[cur][offB[ni][ks]];
#pragma unroll
            for (int mi = 0; mi < MI; mi++)
#pragma unroll
                for (int ni = 0; ni < NI; ni++)
                    acc[mi][ni] = __builtin_amdgcn_mfma_f32_16x16x32_bf16(
                        a[mi], b[ni], acc[mi][ni], 0, 0, 0);
        }
        __syncthreads();                       // drains loads: next buf ready
    }
#undef BSTAGE

    // ---- epilogue. C/D layout: col = lane&15, row = (lane>>4)*4 + reg ----
    const int erow0 = bm + wm + (grp << 2);
    const int ecol0 = bn + wn + fr;
    const bool isV = (EPI == 3) && (bn >= 2 * Dm);   // uniform per block
#pragma unroll
    for (int ni = 0; ni < NI; ni++) {
        const int ccol = ecol0 + ni * 16;
        const float bv = bias[ccol];
#pragma unroll
        for (int mi = 0; mi < MI; mi++) {
            if (isV) {
                // V columns -> transposed bf16 buffer vt[b][h*64+d][n]
                ushort4 o;
                o.x = f2bf(acc[mi][ni][0] + bv);
                o.y = f2bf(acc[mi][ni][1] + bv);
                o.z = f2bf(acc[mi][ni][2] + bv);
                o.w = f2bf(acc[mi][ni][3] + bv);
                const int nrow = erow0 + mi * 16;        // multiple of 4
                const int bb_  = nrow >> 11, nn = nrow & 2047;
                const int hd   = ccol - 2 * Dm;
                *(ushort4*)&vt[((size_t)(bb_ * (Hh * DHd) + hd)) * Nseq + nn] = o;
            } else {
#pragma unroll
                for (int r = 0; r < 4; r++) {
                    const size_t idx = (size_t)(erow0 + mi * 16 + r) * Nn + ccol;
                    float v = acc[mi][ni][r] + bv;
                    if (EPI == 1) v += res[idx];
                    if (EPI == 2) {
                        v = 0.5f * v * (1.0f + erff(v * 0.70710678118f));
                        ((u16*)Cout)[idx] = f2bf(v);
                    } else if (EPI == 3) {
                        ((u16*)Cout)[idx] = f2bf(v);
                    } else {
                        ((float*)Cout)[idx] = v;
                    }
                }
            }
        }
    }
}

// ---------------------------------------------------------------------------
// Flash attention, MFMA, swapped QK^T + fixed-max softmax, 2-batch fold.
// Grid 512: id = b2*256 + (h*16 + qt); block handles batches {b2, b2+2} for
// one (h, 128-q tile) -> bias tile loaded ONCE per K-tile, reused for both
// batches; the b2=0/1 blocks sharing (h,qt) are co-resident (ids g, g+256,
// same XCD mod 8) so their bias reads share L2.
// Per kt: step A computes batch0 on buf0 while staging batch1 -> buf1;
// step B computes batch1 on buf1 while staging next-kt batch0 -> buf0.
// ---------------------------------------------------------------------------
__global__ __launch_bounds__(256, 2) void fattn_kernel(
    const u16* __restrict__ qkv, const u16* __restrict__ vtg,
    const float* __restrict__ sbias, u16* __restrict__ out)
{
    __shared__ u16 Ks[2][4096];   // K-tile [m 64][d 64] bf16, chunk-swizzled
    __shared__ u16 Vs[2][4096];   // V^T-tile [d 64][m 64] bf16, chunk-swizzled
    __shared__ u16 Ps[8192];      // P: 4 waves x [32 q][64 m], chunk-swizzled

    const int tid  = threadIdx.x;
    const int lane = tid & 63;
    const int w    = tid >> 6;          // wave 0..3
    const int id   = blockIdx.x;
    const int b2   = id >> 8;           // batch pair selector
    const int g    = id & 255;
    const int qt   = g & 15;
    const int h    = g >> 4;
    const int n0   = qt * 128;
    const int bA   = b2;                // batch of step A
    const int bB   = b2 + 2;            // batch of step B

    const int grp = lane >> 4;          // 16-lane group 0..3
    const int fr  = lane & 15;

    const size_t rs = 3 * Dm;           // qkv row stride (u16 units)
    const u16* qkA = qkv + (size_t)bA * Nseq * rs + h * DHd;
    const u16* qkB = qkv + (size_t)bB * Nseq * rs + h * DHd;

    // ---- Q fragments in registers (32 rows per wave per batch) ----
    bf16x8 qfA[2][2], qfB[2][2];
#pragma unroll
    for (int rb = 0; rb < 2; rb++)
#pragma unroll
        for (int cc = 0; cc < 2; cc++) {
            const size_t ro = (size_t)(n0 + w*32 + rb*16 + fr) * rs + cc*32 + grp*8;
            qfA[rb][cc] = *(const bf16x8*)(qkA + ro);
            qfB[rb][cc] = *(const bf16x8*)(qkB + ro);
        }

    // ---- staging source addresses (pre-swizzled chunk) ----
    const int r_st = w*8 + (lane >> 3);         // row within tile (instr1: +32)
    const int c8   = (lane & 7) ^ (r_st & 7);
    const u16* kpA = qkA + Dm + (size_t)r_st * rs + c8*8;
    const u16* kpB = qkB + Dm + (size_t)r_st * rs + c8*8;
    const u16* vpA = vtg + ((size_t)(bA*Hh + h)*DHd + r_st) * Nseq + c8*8;
    const u16* vpB = vtg + ((size_t)(bB*Hh + h)*DHd + r_st) * Nseq + c8*8;

#define FSTAGE(bufi, kp, vp) do {                              \
    GLL((kp),                   &Ks[bufi][w*512]);             \
    GLL((kp) + 32*rs,           &Ks[bufi][2048 + w*512]);      \
    GLL((vp),                   &Vs[bufi][w*512]);             \
    GLL((vp) + (size_t)32*Nseq, &Vs[bufi][2048 + w*512]);      \
} while (0)

    // ---- fragment read offsets (u16 units, constant per lane) ----
    int offKV[4][2];
#pragma unroll
    for (int ni = 0; ni < 4; ni++)
#pragma unroll
        for (int cc = 0; cc < 2; cc++)
            offKV[ni][cc] = (ni*16 + fr)*64 + (((grp | (cc<<2)) ^ (fr&7)) << 3);
    const int psbase = w*2048 + fr*64;
    int offP[2][2];
#pragma unroll
    for (int rb = 0; rb < 2; rb++)
#pragma unroll
        for (int cc = 0; cc < 2; cc++)
            offP[rb][cc] = psbase + rb*1024 + (((grp | (cc<<2)) ^ (fr&7)) << 3);

    const float* bpr = sbias + ((size_t)h*Nseq + (n0 + w*32 + fr))*Nseq + grp*4;

    f32x4 acc_oA[2][4] = {}, acc_oB[2][4] = {};
    float l_rA[2] = {0.f, 0.f}, l_rB[2] = {0.f, 0.f};
    float4 bb[2][4];

// compute one (batch, kv-tile) step on buffer KB with Q=QFa, acc=ACCa, l=LRa
#define FSTEP(KB, QFa, ACCa, LRa) do {                                        \
    f32x4 acc_s[2][4] = {};                                                   \
    _Pragma("unroll")                                                         \
    for (int ni = 0; ni < 4; ni++) {                                          \
        bf16x8 k0 = *(const bf16x8*)&Ks[KB][offKV[ni][0]];                    \
        bf16x8 k1 = *(const bf16x8*)&Ks[KB][offKV[ni][1]];                    \
        acc_s[0][ni] = __builtin_amdgcn_mfma_f32_16x16x32_bf16(k0, QFa[0][0], acc_s[0][ni], 0, 0, 0); \
        acc_s[0][ni] = __builtin_amdgcn_mfma_f32_16x16x32_bf16(k1, QFa[0][1], acc_s[0][ni], 0, 0, 0); \
        acc_s[1][ni] = __builtin_amdgcn_mfma_f32_16x16x32_bf16(k0, QFa[1][0], acc_s[1][ni], 0, 0, 0); \
        acc_s[1][ni] = __builtin_amdgcn_mfma_f32_16x16x32_bf16(k1, QFa[1][1], acc_s[1][ni], 0, 0, 0); \
    }                                                                         \
    _Pragma("unroll")                                                         \
    for (int rb = 0; rb < 2; rb++) {                                          \
        float lacc = 0.f;                                                     \
        _Pragma("unroll")                                                     \
        for (int ni = 0; ni < 4; ni++) {                                      \
            float p0 = __expf(fmaf(acc_s[rb][ni][0], 0.125f, bb[rb][ni].x) - MFIX); \
            float p1 = __expf(fmaf(acc_s[rb][ni][1], 0.125f, bb[rb][ni].y) - MFIX); \
            float p2 = __expf(fmaf(acc_s[rb][ni][2], 0.125f, bb[rb][ni].z) - MFIX); \
            float p3 = __expf(fmaf(acc_s[rb][ni][3], 0.125f, bb[rb][ni].w) - MFIX); \
            ushort4 o;                                                        \
            o.x = f2bf(p0); o.y = f2bf(p1); o.z = f2bf(p2); o.w = f2bf(p3);   \
            const int slot = (ni*2 + (grp>>1)) ^ (fr & 7);                    \
            *(ushort4*)&Ps[psbase + rb*1024 + slot*8 + (grp&1)*4] = o;        \
            lacc += (p0 + p1) + (p2 + p3);                                    \
        }                                                                     \
        LRa[rb] += lacc;                                                      \
    }                                                                         \
    bf16x8 pf[2][2];                                                          \
    _Pragma("unroll")                                                         \
    for (int rb = 0; rb < 2; rb++) {                                          \
        pf[rb][0] = *(const bf16x8*)&Ps[offP[rb][0]];                         \
        pf[rb][1] = *(const bf16x8*)&Ps[offP[rb][1]];                         \
    }                                                                         \
    _Pragma("unroll")                                                         \
    for (int ni = 0; ni < 4; ni++) {                                          \
        bf16x8 v0 = *(const bf16x8*)&Vs[KB][offKV[ni][0]];                    \
        bf16x8 v1 = *(const bf16x8*)&Vs[KB][offKV[ni][1]];                    \
        ACCa[0][ni] = __builtin_amdgcn_mfma_f32_16x16x32_bf16(pf[0][0], v0, ACCa[0][ni], 0, 0, 0); \
        ACCa[0][ni] = __builtin_amdgcn_mfma_f32_16x16x32_bf16(pf[0][1], v1, ACCa[0][ni], 0, 0, 0); \
        ACCa[1][ni] = __builtin_amdgcn_mfma_f32_16x16x32_bf16(pf[1][0], v0, ACCa[1][ni], 0, 0, 0); \
        ACCa[1][ni] = __builtin_amdgcn_mfma_f32_16x16x32_bf16(pf[1][1], v1, ACCa[1][ni], 0, 0, 0); \
    }                                                                         \
} while (0)

    // ---- prologue: stage (kt=0, batchA) -> buf0 ----
    FSTAGE(0, kpA, vpA);
    kpA += 64*rs; vpA += 64;
    __syncthreads();

    for (int kt = 0; kt < Nseq/64; kt++) {
        // bias tile for kt (shared by both batches; coalesced float4)
        const float* bp = bpr + kt*64;
#pragma unroll
        for (int rb = 0; rb < 2; rb++)
#pragma unroll
            for (int ni = 0; ni < 4; ni++)
                bb[rb][ni] = *(const float4*)(bp + (size_t)rb*(16*Nseq) + ni*16);

        // step A: stage batchB -> buf1, compute batchA on buf0
        FSTAGE(1, kpB, vpB);
        kpB += 64*rs; vpB += 64;
        FSTEP(0, qfA, acc_oA, l_rA);
        __syncthreads();

        // step B: stage next-kt batchA -> buf0, compute batchB on buf1
        if (kt + 1 < Nseq/64) {
            FSTAGE(0, kpA, vpA);
            kpA += 64*rs; vpA += 64;
        }
        FSTEP(1, qfB, acc_oB, l_rB);
        __syncthreads();
    }
#undef FSTEP
#undef FSTAGE

    // ---- finalize: grp-reduce l, broadcast, store bf16 (per batch) ----
#pragma unroll
    for (int rb = 0; rb < 2; rb++) {
        float lA = l_rA[rb], lB = l_rB[rb];
        lA += __shfl_xor(lA, 16, 64); lA += __shfl_xor(lA, 32, 64);
        lB += __shfl_xor(lB, 16, 64); lB += __shfl_xor(lB, 32, 64);
        l_rA[rb] = lA; l_rB[rb] = lB;
    }
#pragma unroll
    for (int rb = 0; rb < 2; rb++)
#pragma unroll
        for (int r = 0; r < 4; r++) {
            const int srcl = (lane & 48) | (((lane >> 4) & 3) << 2) | r;
            const float invA = 1.0f / __shfl(l_rA[rb], srcl, 64);
            const float invB = 1.0f / __shfl(l_rB[rb], srcl, 64);
            const size_t rowo = (size_t)(n0 + w*32 + rb*16 + grp*4 + r)*Dm + h*DHd + fr;
            u16* oA = out + (size_t)bA*Nseq*Dm + rowo;
            u16* oB = out + (size_t)bB*Nseq*Dm + rowo;
#pragma unroll
            for (int ni = 0; ni < 4; ni++) {
                oA[ni*16] = f2bf(acc_oA[rb][ni][r] * invA);
                oB[ni*16] = f2bf(acc_oB[rb][ni][r] * invB);
            }
        }
}

// ---------------------------------------------------------------------------
// Workspace (<=160MB):
//   [0,48MB)    qkv bf16 (Q,K parts; dead after fattn)
//   [48,64MB)   vT bf16 [b][h*64+d][n] (dead after fattn)
//   [0,64MB)    hidden bf16 (FF phase, overlaps the two above)
//   [96,112MB)  normed bf16 (ln1 out; reused for ln2 out)
//   [112,128MB) attn bf16
//   [128,152MB) transposed bf16 weights: qkv 6MB | out 2MB | ff1 8MB | ff2 8MB
// ---------------------------------------------------------------------------
extern "C" void kernel_launch(void* const* d_in, const int* in_sizes, int n_in,
                              void* d_out, int out_size, void* d_ws, size_t ws_size,
                              hipStream_t stream)
{
    const float* x     = (const float*)d_in[0];
    const float* sbias = (const float*)d_in[1];
    const float* ln1g  = (const float*)d_in[2];
    const float* ln1b  = (const float*)d_in[3];
    const float* ln2g  = (const float*)d_in[4];
    const float* ln2b  = (const float*)d_in[5];
    const float* W_qkv = (const float*)d_in[6];
    const float* b_qkv = (const float*)d_in[7];
    const float* W_out = (const float*)d_in[8];
    const float* b_out = (const float*)d_in[9];
    const float* W_ff1 = (const float*)d_in[10];
    const float* b_ff1 = (const float*)d_in[11];
    const float* W_ff2 = (const float*)d_in[12];
    const float* b_ff2 = (const float*)d_in[13];
    float* out = (float*)d_out;

    char* ws = (char*)d_ws;
    const size_t MB = 1024ull * 1024;
    u16*   qkvb   = (u16*)ws;                    // 48 MB bf16 (Q,K live)
    u16*   vT     = (u16*)(ws + 48 * MB);        // 16 MB bf16 V^T
    u16*   hidden = (u16*)ws;                    // 64 MB bf16 (FF phase)
    u16*   normed = (u16*)(ws + 96 * MB);
    u16*   attn   = (u16*)(ws + 112 * MB);
    u16*   Wqkv_t = (u16*)(ws + 128 * MB);
    u16*   Wout_t = (u16*)(ws + 134 * MB);
    u16*   Wff1_t = (u16*)(ws + 136 * MB);
    u16*   Wff2_t = (u16*)(ws + 144 * MB);

    const int M = Bsz * Nseq;   // 8192

    // 0. weight convert+transpose -> [N][K] bf16
    tcvt_kernel<<<dim3(3*Dm/32, Dm/32), 256, 0, stream>>>(W_qkv, Wqkv_t, Dm, 3*Dm);
    tcvt_kernel<<<dim3(Dm/32,   Dm/32), 256, 0, stream>>>(W_out, Wout_t, Dm, Dm);
    tcvt_kernel<<<dim3(DFFd/32, Dm/32), 256, 0, stream>>>(W_ff1, Wff1_t, Dm, DFFd);
    tcvt_kernel<<<dim3(Dm/32, DFFd/32), 256, 0, stream>>>(W_ff2, Wff2_t, DFFd, Dm);

    // 1. ln1(x) -> normed (bf16)
    ln_kernel<1><<<M, 256, 0, stream>>>(x, ln1g, ln1b, normed);
    // 2. qkv = normed @ W_qkv + b_qkv   (Q,K -> qkvb bf16; V -> vT transposed)
    bgemm_kernel<3, 256, 256><<<dim3(3*Dm/256, M/256), 512, 0, stream>>>(
        normed, Wqkv_t, b_qkv, nullptr, qkvb, vT, M, 3*Dm, Dm);
    // 3. flash attention (MFMA, 2-batch fold) -> attn (bf16)
    fattn_kernel<<<2 * Hh * (Nseq/128), 256, 0, stream>>>(qkvb, vT, sbias, attn);
    // 4. x1 = x + attn @ W_out + b_out -> d_out (fp32)
    bgemm_kernel<1, 256, 128><<<dim3(Dm/128, M/256), 512, 0, stream>>>(
        attn, Wout_t, b_out, x, out, nullptr, M, Dm, Dm);
    // 5. ln2(x1) -> normed (bf16)
    ln_kernel<1><<<M, 256, 0, stream>>>(out, ln2g, ln2b, normed);
    // 6. hidden = gelu(normed @ W_ff1 + b_ff1) (bf16)
    bgemm_kernel<2, 256, 256><<<dim3(DFFd/256, M/256), 512, 0, stream>>>(
        normed, Wff1_t, b_ff1, nullptr, hidden, nullptr, M, DFFd, Dm);
    // 7. out = x1 + hidden @ W_ff2 + b_ff2  (in-place on d_out)
    bgemm_kernel<1, 256, 128><<<dim3(Dm/128, M/256), 512, 0, stream>>>(
        hidden, Wff2_t, b_ff2, out, out, nullptr, M, Dm, DFFd);
}